// Round 2
// baseline (1554.760 us; speedup 1.0000x reference)
//
#include <hip/hip_runtime.h>
#include <cstddef>

#define NS 512
#define NL 5
#define NT 20
#define NE 768
#define NH 64
#define NG 256   // 4*H
#define BK 16

__device__ __forceinline__ float sigf(float x) { return 1.0f / (1.0f + expf(-x)); }
// wave-uniform broadcast of lane k's value via VALU pipe (no LDS traffic)
__device__ __forceinline__ float bcast(float v, int k) {
    return __int_as_float(__builtin_amdgcn_readlane(__float_as_int(v), k));
}

// ---------------------------------------------------------------------------
// Kernel 1 v3: u[s][t][l][g] = x[s][l][t][:] . Uall[s][:][g] + bUall
// LDS-pipe-bound fix: the xs tile reads were wave-uniform ds_read_b128
// broadcasts (10 per k4 = 120 LDS-cyc); x rows are per-wave exclusive, so the
// x tile now lives in 3 VGPRs/lane and is broadcast via v_readlane (VALU).
// Us reads become 4 conflict-free ds_read_b128 per k4 (lane owns 4 contiguous
// cols). One block per stock: 10 waves x 10 rows, 64 lanes x 4 cols = 256.
// Per-element accumulation order is bitwise-identical to v2.
// ---------------------------------------------------------------------------
__global__ __launch_bounds__(640, 3) void k_gemm_u(
    const float* __restrict__ x, const float* __restrict__ U,
    const float* __restrict__ bU, float* __restrict__ u)
{
    __shared__ float Us[BK * NG];     // 16 KB
    const int s = blockIdx.x;
    const int tid = threadIdx.x;
    const int wave = tid >> 6, lane = tid & 63;
    const int r0 = wave * 10;
    const float* xg = x + (size_t)s * (NL * NT * NE);
    const float* Ug = U + (size_t)s * (NE * NG);

    float4 acc[10];
    #pragma unroll
    for (int i = 0; i < 10; ++i) acc[i] = make_float4(0.f, 0.f, 0.f, 0.f);

    const int xrow = lane >> 4;        // 0..3
    const int xk   = lane & 15;        // 0..15

    for (int e0 = 0; e0 < NE; e0 += BK) {
        // stage U tile [16][256] (1024 float4 slots over 640 threads)
        {
            int k = tid >> 6, c4 = (tid & 63) * 4;
            *(float4*)&Us[k * NG + c4] =
                *(const float4*)(Ug + (size_t)(e0 + k) * NG + c4);
            int i2 = tid + 640;
            if (i2 < 1024) {
                int k2 = i2 >> 6, c42 = (i2 & 63) * 4;
                *(float4*)&Us[k2 * NG + c42] =
                    *(const float4*)(Ug + (size_t)(e0 + k2) * NG + c42);
            }
        }
        // per-wave x rows into registers: lane (r<<4|k) holds x[r0+r][e0+k]
        float xA = xg[(size_t)(r0 + xrow) * NE + e0 + xk];          // rows 0..3
        float xB = xg[(size_t)(r0 + 4 + xrow) * NE + e0 + xk];      // rows 4..7
        float xC = xg[(size_t)(r0 + 8 + (xrow & 1)) * NE + e0 + xk];// rows 8,9
        __syncthreads();
        #pragma unroll
        for (int k4 = 0; k4 < BK; k4 += 4) {
            float4 uv0 = *(const float4*)&Us[(k4 + 0) * NG + 4 * lane];
            float4 uv1 = *(const float4*)&Us[(k4 + 1) * NG + 4 * lane];
            float4 uv2 = *(const float4*)&Us[(k4 + 2) * NG + 4 * lane];
            float4 uv3 = *(const float4*)&Us[(k4 + 3) * NG + 4 * lane];
            #pragma unroll
            for (int rr = 0; rr < 10; ++rr) {
                float xsrc = (rr < 4) ? xA : (rr < 8) ? xB : xC;
                const int lb = ((rr < 4) ? rr : (rr < 8) ? (rr - 4) : (rr - 8)) << 4;
                float x0 = bcast(xsrc, lb + k4 + 0);
                float x1 = bcast(xsrc, lb + k4 + 1);
                float x2 = bcast(xsrc, lb + k4 + 2);
                float x3 = bcast(xsrc, lb + k4 + 3);
                acc[rr].x += x0 * uv0.x + x1 * uv1.x + x2 * uv2.x + x3 * uv3.x;
                acc[rr].y += x0 * uv0.y + x1 * uv1.y + x2 * uv2.y + x3 * uv3.y;
                acc[rr].z += x0 * uv0.z + x1 * uv1.z + x2 * uv2.z + x3 * uv3.z;
                acc[rr].w += x0 * uv0.w + x1 * uv1.w + x2 * uv2.w + x3 * uv3.w;
            }
        }
        __syncthreads();
    }
    const float4 bv = *(const float4*)(bU + (size_t)s * NG + 4 * lane);
    #pragma unroll
    for (int rr = 0; rr < 10; ++rr) {
        int r = r0 + rr;
        int l = r / 20, t = r % 20;
        float4 o;
        o.x = acc[rr].x + bv.x;
        o.y = acc[rr].y + bv.y;
        o.z = acc[rr].z + bv.z;
        o.w = acc[rr].w + bv.w;
        *(float4*)(u + (((size_t)s * NT + t) * NL + l) * NG + 4 * lane) = o;
    }
}

// ---------------------------------------------------------------------------
// Kernel 2 (unchanged this round; awaiting counters)
// ---------------------------------------------------------------------------
#define WD    0        // 4096 fl; aliased by W1 after the recurrence
#define W1OFF 0
#define W2OFF 4096     // 4096 fl
#define FULLO 8192     // 6400 fl: o-gates [l][t][h]
#define HS    14592    // 320
#define TQ    14912    // 320: q, then hd
#define CA    15232    // 320: text_vec
#define GATES 15552    // 1280
#define TS    16832    // 100
#define SC    16932    // 100
#define B0    17032    // 64: b1
#define B1    17096    // 64: b2
#define BVV   17160    // 64: V
#define BV1   17224    // 1
#define SMTOT 17228    // 68912 B

__global__ __launch_bounds__(320, 3) void k_stock(
    const float* __restrict__ u, const float* __restrict__ ti,
    const float* __restrict__ Wall, const float* __restrict__ bWall,
    const float* __restrict__ Wd, const float* __restrict__ bWd,
    const float* __restrict__ W1, const float* __restrict__ b1,
    const float* __restrict__ W2, const float* __restrict__ b2,
    const float* __restrict__ V, const float* __restrict__ bV,
    const float* __restrict__ Wih, const float* __restrict__ bih,
    const float* __restrict__ bhh, const float* __restrict__ lin_w,
    const float* __restrict__ lin_b, float* __restrict__ out)
{
    __shared__ float sm[SMTOT];
    const int s = blockIdx.x;
    const int tid = threadIdx.x;
    const int lq = tid >> 6, hh = tid & 63;   // (l, h) item for 320-wide ops
    const int lane = hh;
    const float* ug = u + (size_t)s * NT * NL * NG;

    // ---- init: Wd + W2 + biases to LDS; Wall column + bWd to registers ----
    for (int i = tid; i < 1024; i += 320)
        *(float4*)&sm[WD + i * 4] = *(const float4*)(Wd + (size_t)s * 4096 + i * 4);
    for (int i = tid; i < 1024; i += 320)
        *(float4*)&sm[W2OFF + i * 4] = *(const float4*)(W2 + (size_t)s * 4096 + i * 4);
    if (tid < NH) {
        sm[B0 + tid]  = b1[(size_t)s * NH + tid];
        sm[B1 + tid]  = b2[(size_t)s * NH + tid];
        sm[BVV + tid] = V[(size_t)s * NH + tid];
    }
    if (tid == 0) sm[BV1] = bV[s];
    if (tid < NL * NT) sm[TS + tid] = ti[(size_t)s * NL * NT + tid];
    sm[HS + tid] = 0.0f;
    const float bwd_r = bWd[(size_t)s * NH + hh];
    float c_reg = 0.0f;                 // c[lq][hh], register-resident state
    float wall_r[NH];                   // Wall[:, tid] column (tid<256)
    float bwall_r = 0.0f, uc[NL];
    if (tid < NG) {
        bwall_r = bWall[(size_t)s * NG + tid];
        const float* wp = Wall + (size_t)s * (NH * NG) + tid;
        #pragma unroll
        for (int k = 0; k < NH; ++k) wall_r[k] = wp[(size_t)k * NG];
        #pragma unroll
        for (int l = 0; l < NL; ++l) uc[l] = ug[(size_t)l * NG + tid];
    }
    __syncthreads();

    // ---- TimeLSTM over T steps (gate order f,i,o,c_tmp; ALL sigmoid) ----
    for (int t = 0; t < NT; ++t) {
        float un[NL];
        if (tid < NG) {
            if (t + 1 < NT) {
                #pragma unroll
                for (int l = 0; l < NL; ++l)
                    un[l] = ug[(size_t)((t + 1) * NL + l) * NG + tid];
            } else {
                #pragma unroll
                for (int l = 0; l < NL; ++l) un[l] = 0.0f;
            }
            // h[l][lane] into this wave's own lanes, then readlane-broadcast
            float hreg[NL];
            #pragma unroll
            for (int l = 0; l < NL; ++l) hreg[l] = sm[HS + l * NH + lane];
            float gv[NL];
            #pragma unroll
            for (int l = 0; l < NL; ++l) gv[l] = bwall_r + uc[l];
            #pragma unroll
            for (int k = 0; k < NH; ++k) {
                float w = wall_r[k];
                #pragma unroll
                for (int l = 0; l < NL; ++l)
                    gv[l] += bcast(hreg[l], k) * w;
            }
            #pragma unroll
            for (int l = 0; l < NL; ++l)
                sm[GATES + l * NG + tid] = sigf(gv[l]);
        }
        // c_s1 = tanh(c@Wd + bWd); c broadcast via readlane (wave lq == l)
        float ssum = bwd_r;
        #pragma unroll
        for (int k = 0; k < NH; ++k)
            ssum += bcast(c_reg, k) * sm[WD + k * NH + hh];
        float cs1 = tanhf(ssum);
        float ca = c_reg - cs1 + cs1 * sm[TS + lq * NT + t];
        __syncthreads();
        {
            float f  = sm[GATES + lq * NG + hh];
            float ii = sm[GATES + lq * NG + 64 + hh];
            float oo = sm[GATES + lq * NG + 128 + hh];
            float ct = sm[GATES + lq * NG + 192 + hh];
            float cn = f * ca + ii * ct;
            c_reg = cn;
            sm[HS + tid] = oo * tanhf(cn);
            sm[FULLO + (lq * NT + t) * NH + hh] = oo;
        }
        __syncthreads();
        if (tid < NG) {
            #pragma unroll
            for (int l = 0; l < NL; ++l) uc[l] = un[l];
        }
    }

    // ---- W1 overwrites dead Wd LDS ----
    for (int i = tid; i < 1024; i += 320)
        *(float4*)&sm[W1OFF + i * 4] = *(const float4*)(W1 + (size_t)s * 4096 + i * 4);
    __syncthreads();

    // q = h_fin @ W1 + b1   (320 items)
    {
        float qv = sm[B0 + hh];
        for (int k4 = 0; k4 < NH; k4 += 4) {
            float4 hv = *(const float4*)&sm[HS + lq * NH + k4];
            qv += hv.x * sm[W1OFF + (k4 + 0) * NH + hh]
                + hv.y * sm[W1OFF + (k4 + 1) * NH + hh]
                + hv.z * sm[W1OFF + (k4 + 2) * NH + hh]
                + hv.w * sm[W1OFF + (k4 + 3) * NH + hh];
        }
        sm[TQ + tid] = qv;
    }
    __syncthreads();

    // scores: one wave per (l,t) item; 100 items over 5 waves
    for (int lt = lq; lt < NL * NT; lt += 5) {
        int l = lt / NT;
        float v = sm[TQ + l * NH + lane] + sm[B1 + lane];
        for (int k4 = 0; k4 < NH; k4 += 4) {
            float4 fv = *(const float4*)&sm[FULLO + lt * NH + k4];
            v += fv.x * sm[W2OFF + (k4 + 0) * NH + lane]
               + fv.y * sm[W2OFF + (k4 + 1) * NH + lane]
               + fv.z * sm[W2OFF + (k4 + 2) * NH + lane]
               + fv.w * sm[W2OFF + (k4 + 3) * NH + lane];
        }
        v = tanhf(v) * sm[BVV + lane];
        #pragma unroll
        for (int m = 32; m > 0; m >>= 1) v += __shfl_xor(v, m, 64);
        if (lane == 0) sm[SC + lt] = v + sm[BV1];
    }
    __syncthreads();

    // softmax over t per l
    if (tid < NL) {
        float mx = -1e30f;
        for (int t = 0; t < NT; ++t) mx = fmaxf(mx, sm[SC + tid * NT + t]);
        float sum = 0.0f;
        for (int t = 0; t < NT; ++t) {
            float e = expf(sm[SC + tid * NT + t] - mx);
            sm[SC + tid * NT + t] = e;
            sum += e;
        }
        float inv = 1.0f / sum;
        for (int t = 0; t < NT; ++t) sm[SC + tid * NT + t] *= inv;
    }
    __syncthreads();

    // text_vec -> CA
    {
        float sv = 0.0f;
        #pragma unroll
        for (int t = 0; t < NT; ++t)
            sv += sm[SC + lq * NT + t] * sm[FULLO + (lq * NT + t) * NH + hh];
        sm[CA + tid] = sv;
    }
    __syncthreads();

    // day LSTM: g = tv@Wih + bih + bhh; order i,f,g,o
    if (tid < NG) {
        float bsum = bih[(size_t)s * NG + tid] + bhh[(size_t)s * NG + tid];
        float d[NL];
        #pragma unroll
        for (int l = 0; l < NL; ++l) d[l] = bsum;
        for (int k = 0; k < NH; ++k) {
            float wk = Wih[((size_t)s * NH + k) * NG + tid];
            #pragma unroll
            for (int l = 0; l < NL; ++l)
                d[l] += sm[CA + l * NH + k] * wk;
        }
        #pragma unroll
        for (int l = 0; l < NL; ++l)
            sm[GATES + l * NG + tid] = d[l];
    }
    __syncthreads();
    {
        float gi = sm[GATES + lq * NG + hh];
        float gg = sm[GATES + lq * NG + 128 + hh];
        float go = sm[GATES + lq * NG + 192 + hh];
        float cd = sigf(gi) * tanhf(gg);
        sm[TQ + tid] = sigf(go) * tanhf(cd);    // hd (q is dead)
    }
    __syncthreads();

    // day attention: wave lq handles l=lq (<5)
    {
        float v = sm[B0 + lane] + sm[B1 + lane];
        for (int k4 = 0; k4 < NH; k4 += 4) {
            float4 hv = *(const float4*)&sm[TQ + lq * NH + k4];
            v += hv.x * (sm[W1OFF + (k4 + 0) * NH + lane] + sm[W2OFF + (k4 + 0) * NH + lane])
               + hv.y * (sm[W1OFF + (k4 + 1) * NH + lane] + sm[W2OFF + (k4 + 1) * NH + lane])
               + hv.z * (sm[W1OFF + (k4 + 2) * NH + lane] + sm[W2OFF + (k4 + 2) * NH + lane])
               + hv.w * (sm[W1OFF + (k4 + 3) * NH + lane] + sm[W2OFF + (k4 + 3) * NH + lane]);
        }
        v = tanhf(v) * sm[BVV + lane];
        #pragma unroll
        for (int m = 32; m > 0; m >>= 1) v += __shfl_xor(v, m, 64);
        if (lane == 0) sm[SC + lq] = v + sm[BV1];
    }
    __syncthreads();
    if (tid == 0) {
        float mx = -1e30f;
        for (int l = 0; l < NL; ++l) mx = fmaxf(mx, sm[SC + l]);
        float sum = 0.0f;
        for (int l = 0; l < NL; ++l) {
            float e = expf(sm[SC + l] - mx);
            sm[SC + l] = e;
            sum += e;
        }
        float inv = 1.0f / sum;
        for (int l = 0; l < NL; ++l) sm[SC + l] *= inv;
    }
    __syncthreads();

    if (tid < NH) {
        float fv = 0.0f;
        #pragma unroll
        for (int l = 0; l < NL; ++l)
            fv += sm[SC + l] * sm[TQ + l * NH + tid];
        fv *= lin_w[tid];
        #pragma unroll
        for (int m = 32; m > 0; m >>= 1) fv += __shfl_xor(fv, m, 64);
        if (tid == 0) {
            float val = fv + lin_b[0];
            out[s] = val > 0.0f ? val : 0.01f * val;
        }
    }
}

extern "C" void kernel_launch(void* const* d_in, const int* in_sizes, int n_in,
                              void* d_out, int out_size, void* d_ws, size_t ws_size,
                              hipStream_t stream) {
    (void)in_sizes; (void)n_in; (void)out_size; (void)ws_size;
    const float* x     = (const float*)d_in[0];
    const float* ti    = (const float*)d_in[1];
    const float* Wall  = (const float*)d_in[2];
    const float* bWall = (const float*)d_in[3];
    const float* Uall  = (const float*)d_in[4];
    const float* bUall = (const float*)d_in[5];
    const float* Wd    = (const float*)d_in[6];
    const float* bWd   = (const float*)d_in[7];
    const float* W1    = (const float*)d_in[8];
    const float* b1    = (const float*)d_in[9];
    const float* W2    = (const float*)d_in[10];
    const float* b2    = (const float*)d_in[11];
    const float* V     = (const float*)d_in[12];
    const float* bV    = (const float*)d_in[13];
    const float* Wih   = (const float*)d_in[14];
    const float* bih   = (const float*)d_in[16];
    const float* bhh   = (const float*)d_in[17];
    const float* lin_w = (const float*)d_in[18];
    const float* lin_b = (const float*)d_in[19];
    float* out = (float*)d_out;
    float* u = (float*)d_ws;   // [S][T][L][NG] = 52.4 MB

    k_gemm_u<<<NS, 640, 0, stream>>>(x, Uall, bUall, u);
    k_stock<<<NS, 320, 0, stream>>>(u, ti, Wall, bWall, Wd, bWd, W1, b1, W2, b2,
                                    V, bV, Wih, bih, bhh, lin_w, lin_b, out);
}

// Round 3
// 942.036 us; speedup vs baseline: 1.6504x; 1.6504x over previous
//
#include <hip/hip_runtime.h>
#include <cstddef>

#define NS 512
#define NL 5
#define NT 20
#define NE 768
#define NH 64
#define NG 256   // 4*H

__device__ __forceinline__ float sigf(float x) { return 1.0f / (1.0f + expf(-x)); }
__device__ __forceinline__ float bcast(float v, int k) {
    return __int_as_float(__builtin_amdgcn_readlane(__float_as_int(v), k));
}

typedef __attribute__((ext_vector_type(8))) short short8v;   // 8 bf16 = 4 VGPR
typedef __attribute__((ext_vector_type(4))) float f32x4;

// round-to-nearest-ish fp32 -> bf16 split: x ~= hi + lo, residual ~2^-18 |x|
__device__ __forceinline__ void split_bf16(float x, unsigned short& hi, unsigned short& lo) {
    unsigned int bx = __float_as_uint(x);
    unsigned int h = (bx + 0x8000u) >> 16;
    hi = (unsigned short)h;
    float r = x - __uint_as_float(h << 16);
    lo = (unsigned short)((__float_as_uint(r) + 0x8000u) >> 16);
}

// ---------------------------------------------------------------------------
// Kernel 1 v4 (MFMA, 3xbf16 split): u[s][t][l][g] = x-row . Uall[s][:,g] + bU
// One block per stock. M=128 (rows 100..127 zero-padded), N=256, K=768.
// 8 waves; wave (wm = w&1, wn = w>>1) owns M-tiles wm*4+{0..3} and N-tiles
// wn*4+{0..3} of 16x16 C-tiles -> acc 4x4 f32x4 (64 VGPR).
// Per K-step (32): stage A(128x32) and B(32x256) as hi/lo bf16 fragments in
// LDS (fragment-major: one conflict-free ds_read_b128 per frag), 3 MFMAs per
// C-tile (hi*hi + hi*lo + lo*hi). Next step's global loads issue before the
// MFMA block to hide HBM latency (1 block/CU).
// ---------------------------------------------------------------------------
__global__ __launch_bounds__(512, 2) void k_gemm_u(
    const float* __restrict__ x, const float* __restrict__ U,
    const float* __restrict__ bU, float* __restrict__ u)
{
    __shared__ unsigned short Af[8 * 2 * 64 * 8];    // [mtile][hl][lane][8] = 16 KB
    __shared__ unsigned short Bf[16 * 2 * 64 * 8];   // [ntile][hl][lane][8] = 32 KB
    const int s = blockIdx.x;
    const int tid = threadIdx.x;
    const int wave = tid >> 6, lane = tid & 63;
    const int wm = wave & 1, wn = wave >> 1;
    const float* xg = x + (size_t)s * (NL * NT * NE);
    const float* Ug = U + (size_t)s * (NE * NG);

    f32x4 acc[4][4] = {};

    // A staging: thread -> chunk (row, b): 8 floats x[row][k0+8b .. +7]
    const int arow = tid >> 2, ab = tid & 3;
    const unsigned int a_off0 = (((unsigned)(arow >> 4) * 2 + 0) * 64 + ((arow & 15) + 16 * ab)) * 8;
    const unsigned int a_off1 = a_off0 + 64 * 8;     // hl=1
    // B staging: thread -> chunks (col, bq1) and (col, bq1+2)
    const int bcol = tid & 255, bq1 = tid >> 8;
    const unsigned int b_base = (unsigned)(bcol >> 4) * 2 * 64 * 8;
    const unsigned int b_off1h = b_base + ((bcol & 15) + 16 * bq1) * 8;
    const unsigned int b_off1l = b_off1h + 64 * 8;
    const unsigned int b_off2h = b_base + ((bcol & 15) + 16 * (bq1 + 2)) * 8;
    const unsigned int b_off2l = b_off2h + 64 * 8;

    float av[8], bv1[8], bv2[8];
    // prologue: loads for step 0
    {
        const float* pa = xg + (size_t)arow * NE + ab * 8;
        if (arow < 100) {
            float4 q0 = *(const float4*)pa, q1 = *(const float4*)(pa + 4);
            av[0]=q0.x; av[1]=q0.y; av[2]=q0.z; av[3]=q0.w;
            av[4]=q1.x; av[5]=q1.y; av[6]=q1.z; av[7]=q1.w;
        } else {
            #pragma unroll
            for (int j = 0; j < 8; ++j) av[j] = 0.0f;
        }
        const float* pb = Ug + bcol;
        #pragma unroll
        for (int j = 0; j < 8; ++j) {
            bv1[j] = pb[(size_t)(8 * bq1 + j) * NG];
            bv2[j] = pb[(size_t)(8 * bq1 + 16 + j) * NG];
        }
    }

    for (int st = 0; st < 24; ++st) {
        // ---- split staged registers into hi/lo bf16, write fragment LDS ----
        {
            unsigned short h[8], l[8];
            #pragma unroll
            for (int j = 0; j < 8; ++j) split_bf16(av[j], h[j], l[j]);
            uint4 ph, pl;
            ph.x = h[0] | (h[1] << 16); ph.y = h[2] | (h[3] << 16);
            ph.z = h[4] | (h[5] << 16); ph.w = h[6] | (h[7] << 16);
            pl.x = l[0] | (l[1] << 16); pl.y = l[2] | (l[3] << 16);
            pl.z = l[4] | (l[5] << 16); pl.w = l[6] | (l[7] << 16);
            *(uint4*)&Af[a_off0] = ph;
            *(uint4*)&Af[a_off1] = pl;
            #pragma unroll
            for (int j = 0; j < 8; ++j) split_bf16(bv1[j], h[j], l[j]);
            ph.x = h[0] | (h[1] << 16); ph.y = h[2] | (h[3] << 16);
            ph.z = h[4] | (h[5] << 16); ph.w = h[6] | (h[7] << 16);
            pl.x = l[0] | (l[1] << 16); pl.y = l[2] | (l[3] << 16);
            pl.z = l[4] | (l[5] << 16); pl.w = l[6] | (l[7] << 16);
            *(uint4*)&Bf[b_off1h] = ph;
            *(uint4*)&Bf[b_off1l] = pl;
            #pragma unroll
            for (int j = 0; j < 8; ++j) split_bf16(bv2[j], h[j], l[j]);
            ph.x = h[0] | (h[1] << 16); ph.y = h[2] | (h[3] << 16);
            ph.z = h[4] | (h[5] << 16); ph.w = h[6] | (h[7] << 16);
            pl.x = l[0] | (l[1] << 16); pl.y = l[2] | (l[3] << 16);
            pl.z = l[4] | (l[5] << 16); pl.w = l[6] | (l[7] << 16);
            *(uint4*)&Bf[b_off2h] = ph;
            *(uint4*)&Bf[b_off2l] = pl;
        }
        __syncthreads();

        // ---- issue next step's global loads (latency hides under MFMA) ----
        if (st + 1 < 24) {
            const int k0 = (st + 1) * 32;
            const float* pa = xg + (size_t)arow * NE + k0 + ab * 8;
            if (arow < 100) {
                float4 q0 = *(const float4*)pa, q1 = *(const float4*)(pa + 4);
                av[0]=q0.x; av[1]=q0.y; av[2]=q0.z; av[3]=q0.w;
                av[4]=q1.x; av[5]=q1.y; av[6]=q1.z; av[7]=q1.w;
            } else {
                #pragma unroll
                for (int j = 0; j < 8; ++j) av[j] = 0.0f;
            }
            const float* pb = Ug + (size_t)k0 * NG + bcol;
            #pragma unroll
            for (int j = 0; j < 8; ++j) {
                bv1[j] = pb[(size_t)(8 * bq1 + j) * NG];
                bv2[j] = pb[(size_t)(8 * bq1 + 16 + j) * NG];
            }
        }

        // ---- fragments + MFMA ----
        short8v ah[4], al[4];
        #pragma unroll
        for (int mi = 0; mi < 4; ++mi) {
            const unsigned int mt = wm * 4 + mi;
            ah[mi] = *(const short8v*)&Af[(mt * 2 + 0) * 512 + lane * 8];
            al[mi] = *(const short8v*)&Af[(mt * 2 + 1) * 512 + lane * 8];
        }
        #pragma unroll
        for (int ni = 0; ni < 4; ++ni) {
            const unsigned int nt = wn * 4 + ni;
            short8v bh = *(const short8v*)&Bf[(nt * 2 + 0) * 512 + lane * 8];
            short8v bl = *(const short8v*)&Bf[(nt * 2 + 1) * 512 + lane * 8];
            #pragma unroll
            for (int mi = 0; mi < 4; ++mi) {
                acc[mi][ni] = __builtin_amdgcn_mfma_f32_16x16x32_bf16(ah[mi], bh, acc[mi][ni], 0, 0, 0);
                acc[mi][ni] = __builtin_amdgcn_mfma_f32_16x16x32_bf16(ah[mi], bl, acc[mi][ni], 0, 0, 0);
                acc[mi][ni] = __builtin_amdgcn_mfma_f32_16x16x32_bf16(al[mi], bh, acc[mi][ni], 0, 0, 0);
            }
        }
        __syncthreads();
    }

    // ---- epilogue: bias + scattered store (C/D: col=lane&15, row=4*(l>>4)+r) ----
    const int c_sub = 4 * (lane >> 4);
    #pragma unroll
    for (int ni = 0; ni < 4; ++ni) {
        const int gcol = wn * 64 + ni * 16 + (lane & 15);
        const float bb = bU[(size_t)s * NG + gcol];
        #pragma unroll
        for (int mi = 0; mi < 4; ++mi) {
            const int grow0 = wm * 64 + mi * 16 + c_sub;
            #pragma unroll
            for (int r = 0; r < 4; ++r) {
                const int grow = grow0 + r;
                if (grow < 100) {
                    const int ld = grow / 20, td = grow % 20;
                    u[(((size_t)s * NT + td) * NL + ld) * NG + gcol] = acc[mi][ni][r] + bb;
                }
            }
        }
    }
}

// ---------------------------------------------------------------------------
// Kernel 2 (unchanged; awaiting counters)
// ---------------------------------------------------------------------------
#define WD    0        // 4096 fl; aliased by W1 after the recurrence
#define W1OFF 0
#define W2OFF 4096     // 4096 fl
#define FULLO 8192     // 6400 fl: o-gates [l][t][h]
#define HS    14592    // 320
#define TQ    14912    // 320: q, then hd
#define CA    15232    // 320: text_vec
#define GATES 15552    // 1280
#define TS    16832    // 100
#define SC    16932    // 100
#define B0    17032    // 64: b1
#define B1    17096    // 64: b2
#define BVV   17160    // 64: V
#define BV1   17224    // 1
#define SMTOT 17228    // 68912 B

__global__ __launch_bounds__(320, 3) void k_stock(
    const float* __restrict__ u, const float* __restrict__ ti,
    const float* __restrict__ Wall, const float* __restrict__ bWall,
    const float* __restrict__ Wd, const float* __restrict__ bWd,
    const float* __restrict__ W1, const float* __restrict__ b1,
    const float* __restrict__ W2, const float* __restrict__ b2,
    const float* __restrict__ V, const float* __restrict__ bV,
    const float* __restrict__ Wih, const float* __restrict__ bih,
    const float* __restrict__ bhh, const float* __restrict__ lin_w,
    const float* __restrict__ lin_b, float* __restrict__ out)
{
    __shared__ float sm[SMTOT];
    const int s = blockIdx.x;
    const int tid = threadIdx.x;
    const int lq = tid >> 6, hh = tid & 63;
    const int lane = hh;
    const float* ug = u + (size_t)s * NT * NL * NG;

    for (int i = tid; i < 1024; i += 320)
        *(float4*)&sm[WD + i * 4] = *(const float4*)(Wd + (size_t)s * 4096 + i * 4);
    for (int i = tid; i < 1024; i += 320)
        *(float4*)&sm[W2OFF + i * 4] = *(const float4*)(W2 + (size_t)s * 4096 + i * 4);
    if (tid < NH) {
        sm[B0 + tid]  = b1[(size_t)s * NH + tid];
        sm[B1 + tid]  = b2[(size_t)s * NH + tid];
        sm[BVV + tid] = V[(size_t)s * NH + tid];
    }
    if (tid == 0) sm[BV1] = bV[s];
    if (tid < NL * NT) sm[TS + tid] = ti[(size_t)s * NL * NT + tid];
    sm[HS + tid] = 0.0f;
    const float bwd_r = bWd[(size_t)s * NH + hh];
    float c_reg = 0.0f;
    float wall_r[NH];
    float bwall_r = 0.0f, uc[NL];
    if (tid < NG) {
        bwall_r = bWall[(size_t)s * NG + tid];
        const float* wp = Wall + (size_t)s * (NH * NG) + tid;
        #pragma unroll
        for (int k = 0; k < NH; ++k) wall_r[k] = wp[(size_t)k * NG];
        #pragma unroll
        for (int l = 0; l < NL; ++l) uc[l] = ug[(size_t)l * NG + tid];
    }
    __syncthreads();

    for (int t = 0; t < NT; ++t) {
        float un[NL];
        if (tid < NG) {
            if (t + 1 < NT) {
                #pragma unroll
                for (int l = 0; l < NL; ++l)
                    un[l] = ug[(size_t)((t + 1) * NL + l) * NG + tid];
            } else {
                #pragma unroll
                for (int l = 0; l < NL; ++l) un[l] = 0.0f;
            }
            float hreg[NL];
            #pragma unroll
            for (int l = 0; l < NL; ++l) hreg[l] = sm[HS + l * NH + lane];
            float gv[NL];
            #pragma unroll
            for (int l = 0; l < NL; ++l) gv[l] = bwall_r + uc[l];
            #pragma unroll
            for (int k = 0; k < NH; ++k) {
                float w = wall_r[k];
                #pragma unroll
                for (int l = 0; l < NL; ++l)
                    gv[l] += bcast(hreg[l], k) * w;
            }
            #pragma unroll
            for (int l = 0; l < NL; ++l)
                sm[GATES + l * NG + tid] = sigf(gv[l]);
        }
        float ssum = bwd_r;
        #pragma unroll
        for (int k = 0; k < NH; ++k)
            ssum += bcast(c_reg, k) * sm[WD + k * NH + hh];
        float cs1 = tanhf(ssum);
        float ca = c_reg - cs1 + cs1 * sm[TS + lq * NT + t];
        __syncthreads();
        {
            float f  = sm[GATES + lq * NG + hh];
            float ii = sm[GATES + lq * NG + 64 + hh];
            float oo = sm[GATES + lq * NG + 128 + hh];
            float ct = sm[GATES + lq * NG + 192 + hh];
            float cn = f * ca + ii * ct;
            c_reg = cn;
            sm[HS + tid] = oo * tanhf(cn);
            sm[FULLO + (lq * NT + t) * NH + hh] = oo;
        }
        __syncthreads();
        if (tid < NG) {
            #pragma unroll
            for (int l = 0; l < NL; ++l) uc[l] = un[l];
        }
    }

    for (int i = tid; i < 1024; i += 320)
        *(float4*)&sm[W1OFF + i * 4] = *(const float4*)(W1 + (size_t)s * 4096 + i * 4);
    __syncthreads();

    {
        float qv = sm[B0 + hh];
        for (int k4 = 0; k4 < NH; k4 += 4) {
            float4 hv = *(const float4*)&sm[HS + lq * NH + k4];
            qv += hv.x * sm[W1OFF + (k4 + 0) * NH + hh]
                + hv.y * sm[W1OFF + (k4 + 1) * NH + hh]
                + hv.z * sm[W1OFF + (k4 + 2) * NH + hh]
                + hv.w * sm[W1OFF + (k4 + 3) * NH + hh];
        }
        sm[TQ + tid] = qv;
    }
    __syncthreads();

    for (int lt = lq; lt < NL * NT; lt += 5) {
        int l = lt / NT;
        float v = sm[TQ + l * NH + lane] + sm[B1 + lane];
        for (int k4 = 0; k4 < NH; k4 += 4) {
            float4 fv = *(const float4*)&sm[FULLO + lt * NH + k4];
            v += fv.x * sm[W2OFF + (k4 + 0) * NH + lane]
               + fv.y * sm[W2OFF + (k4 + 1) * NH + lane]
               + fv.z * sm[W2OFF + (k4 + 2) * NH + lane]
               + fv.w * sm[W2OFF + (k4 + 3) * NH + lane];
        }
        v = tanhf(v) * sm[BVV + lane];
        #pragma unroll
        for (int m = 32; m > 0; m >>= 1) v += __shfl_xor(v, m, 64);
        if (lane == 0) sm[SC + lt] = v + sm[BV1];
    }
    __syncthreads();

    if (tid < NL) {
        float mx = -1e30f;
        for (int t = 0; t < NT; ++t) mx = fmaxf(mx, sm[SC + tid * NT + t]);
        float sum = 0.0f;
        for (int t = 0; t < NT; ++t) {
            float e = expf(sm[SC + tid * NT + t] - mx);
            sm[SC + tid * NT + t] = e;
            sum += e;
        }
        float inv = 1.0f / sum;
        for (int t = 0; t < NT; ++t) sm[SC + tid * NT + t] *= inv;
    }
    __syncthreads();

    {
        float sv = 0.0f;
        #pragma unroll
        for (int t = 0; t < NT; ++t)
            sv += sm[SC + lq * NT + t] * sm[FULLO + (lq * NT + t) * NH + hh];
        sm[CA + tid] = sv;
    }
    __syncthreads();

    if (tid < NG) {
        float bsum = bih[(size_t)s * NG + tid] + bhh[(size_t)s * NG + tid];
        float d[NL];
        #pragma unroll
        for (int l = 0; l < NL; ++l) d[l] = bsum;
        for (int k = 0; k < NH; ++k) {
            float wk = Wih[((size_t)s * NH + k) * NG + tid];
            #pragma unroll
            for (int l = 0; l < NL; ++l)
                d[l] += sm[CA + l * NH + k] * wk;
        }
        #pragma unroll
        for (int l = 0; l < NL; ++l)
            sm[GATES + l * NG + tid] = d[l];
    }
    __syncthreads();
    {
        float gi = sm[GATES + lq * NG + hh];
        float gg = sm[GATES + lq * NG + 128 + hh];
        float go = sm[GATES + lq * NG + 192 + hh];
        float cd = sigf(gi) * tanhf(gg);
        sm[TQ + tid] = sigf(go) * tanhf(cd);
    }
    __syncthreads();

    {
        float v = sm[B0 + lane] + sm[B1 + lane];
        for (int k4 = 0; k4 < NH; k4 += 4) {
            float4 hv = *(const float4*)&sm[TQ + lq * NH + k4];
            v += hv.x * (sm[W1OFF + (k4 + 0) * NH + lane] + sm[W2OFF + (k4 + 0) * NH + lane])
               + hv.y * (sm[W1OFF + (k4 + 1) * NH + lane] + sm[W2OFF + (k4 + 1) * NH + lane])
               + hv.z * (sm[W1OFF + (k4 + 2) * NH + lane] + sm[W2OFF + (k4 + 2) * NH + lane])
               + hv.w * (sm[W1OFF + (k4 + 3) * NH + lane] + sm[W2OFF + (k4 + 3) * NH + lane]);
        }
        v = tanhf(v) * sm[BVV + lane];
        #pragma unroll
        for (int m = 32; m > 0; m >>= 1) v += __shfl_xor(v, m, 64);
        if (lane == 0) sm[SC + lq] = v + sm[BV1];
    }
    __syncthreads();
    if (tid == 0) {
        float mx = -1e30f;
        for (int l = 0; l < NL; ++l) mx = fmaxf(mx, sm[SC + l]);
        float sum = 0.0f;
        for (int l = 0; l < NL; ++l) {
            float e = expf(sm[SC + l] - mx);
            sm[SC + l] = e;
            sum += e;
        }
        float inv = 1.0f / sum;
        for (int l = 0; l < NL; ++l) sm[SC + l] *= inv;
    }
    __syncthreads();

    if (tid < NH) {
        float fv = 0.0f;
        #pragma unroll
        for (int l = 0; l < NL; ++l)
            fv += sm[SC + l] * sm[TQ + l * NH + tid];
        fv *= lin_w[tid];
        #pragma unroll
        for (int m = 32; m > 0; m >>= 1) fv += __shfl_xor(fv, m, 64);
        if (tid == 0) {
            float val = fv + lin_b[0];
            out[s] = val > 0.0f ? val : 0.01f * val;
        }
    }
}

extern "C" void kernel_launch(void* const* d_in, const int* in_sizes, int n_in,
                              void* d_out, int out_size, void* d_ws, size_t ws_size,
                              hipStream_t stream) {
    (void)in_sizes; (void)n_in; (void)out_size; (void)ws_size;
    const float* x     = (const float*)d_in[0];
    const float* ti    = (const float*)d_in[1];
    const float* Wall  = (const float*)d_in[2];
    const float* bWall = (const float*)d_in[3];
    const float* Uall  = (const float*)d_in[4];
    const float* bUall = (const float*)d_in[5];
    const float* Wd    = (const float*)d_in[6];
    const float* bWd   = (const float*)d_in[7];
    const float* W1    = (const float*)d_in[8];
    const float* b1    = (const float*)d_in[9];
    const float* W2    = (const float*)d_in[10];
    const float* b2    = (const float*)d_in[11];
    const float* V     = (const float*)d_in[12];
    const float* bV    = (const float*)d_in[13];
    const float* Wih   = (const float*)d_in[14];
    const float* bih   = (const float*)d_in[16];
    const float* bhh   = (const float*)d_in[17];
    const float* lin_w = (const float*)d_in[18];
    const float* lin_b = (const float*)d_in[19];
    float* out = (float*)d_out;
    float* u = (float*)d_ws;   // [S][T][L][NG] = 52.4 MB

    k_gemm_u<<<NS, 512, 0, stream>>>(x, Uall, bUall, u);
    k_stock<<<NS, 320, 0, stream>>>(u, ti, Wall, bWall, Wd, bWd, W1, b1, W2, b2,
                                    V, bV, Wih, bih, bhh, lin_w, lin_b, out);
}